// Round 1
// baseline (550.398 us; speedup 1.0000x reference)
//
#include <hip/hip_runtime.h>
#include <cstdint>

#define BB 256
#define TT 1000
#define DD 256
#define SS 10
#define HH 64
#define CC 100

// ---------------------------------------------------------------------------
// Kernel 1: input projection  xp[b,t,h] = x[b,t,:] . W_ih[s(t),h,:] + b_ih[s,h]
// Per segment s: GEMM [25600 x 256] x [256 x 64]. Tiled 64x64, K-chunks of 64.
// LDS layout [row][68] (pad) so ds_read_b128 along k is aligned & ~conflict-free.
// grid = (400 row-tiles, 10 segments), block = 256 threads, each thread 4x4 out.
// ---------------------------------------------------------------------------
__global__ __launch_bounds__(256) void proj_kernel(
    const float* __restrict__ x, const float* __restrict__ W_ih,
    const float* __restrict__ b_ih, float* __restrict__ xp) {
  __shared__ float As[64][68];
  __shared__ float Bs[64][68];
  const int s = blockIdx.y;
  const int r0 = blockIdx.x * 64;   // row within segment, r = b*CC + c
  const int tid = threadIdx.x;
  const int ty = tid >> 4, tx = tid & 15;
  const int ty4 = ty * 4, tx4 = tx * 4;
  float acc[4][4] = {{0.f, 0.f, 0.f, 0.f}};

  for (int kc = 0; kc < 4; ++kc) {
    // stage x-tile and W-tile: 64 rows x 64 k each, 1024 float4s / 256 thr
#pragma unroll
    for (int m = 0; m < 4; ++m) {
      int f = m * 256 + tid;
      int row = f >> 4, kq = f & 15;
      int r = r0 + row;
      int b = r / CC, c = r - b * CC;
      const float4 av = *(const float4*)(
          x + ((size_t)b * TT + s * CC + c) * DD + kc * 64 + kq * 4);
      *(float4*)&As[row][kq * 4] = av;
      const float4 wv = *(const float4*)(
          W_ih + ((size_t)s * HH + row) * DD + kc * 64 + kq * 4);
      *(float4*)&Bs[row][kq * 4] = wv;
    }
    __syncthreads();
#pragma unroll 4
    for (int k = 0; k < 64; k += 4) {
      float4 a[4], w[4];
#pragma unroll
      for (int i = 0; i < 4; ++i) a[i] = *(const float4*)&As[ty4 + i][k];
#pragma unroll
      for (int j = 0; j < 4; ++j) w[j] = *(const float4*)&Bs[tx4 + j][k];
#pragma unroll
      for (int i = 0; i < 4; ++i)
#pragma unroll
        for (int j = 0; j < 4; ++j)
          acc[i][j] += a[i].x * w[j].x + a[i].y * w[j].y +
                       a[i].z * w[j].z + a[i].w * w[j].w;
    }
    __syncthreads();
  }

  const float4 bias = *(const float4*)(b_ih + s * HH + tx4);
#pragma unroll
  for (int i = 0; i < 4; ++i) {
    int r = r0 + ty4 + i;
    int b = r / CC, c = r - b * CC;
    float4 o;
    o.x = acc[i][0] + bias.x;
    o.y = acc[i][1] + bias.y;
    o.z = acc[i][2] + bias.z;
    o.w = acc[i][3] + bias.w;
    *(float4*)(xp + ((size_t)b * TT + s * CC + c) * HH + tx4) = o;
  }
}

// ---------------------------------------------------------------------------
// Kernel 2: recurrence + fused head. One block (one wave) per batch element.
// Lane i owns h[i]; W_hh[s] row i in 64 VGPRs; h broadcast via LDS ring
// hist[c][68] (pad 68: b128-aligned broadcast reads; write 2-way = free).
// After each segment's 100 steps, head pass reduces hist rows against fc_w
// (wave-uniform -> s_loads) and stores sigmoid(y) coalesced.
// ---------------------------------------------------------------------------
__global__ __launch_bounds__(64) void rnn_kernel(
    const float* __restrict__ xp, const float* __restrict__ W_hh,
    const float* __restrict__ b_hh, const float* __restrict__ fc_w,
    const float* __restrict__ fc_b, float* __restrict__ y) {
  __shared__ float hist[CC][68];
  const int b = blockIdx.x;
  const int lane = threadIdx.x;

  hist[CC - 1][lane] = 0.f;  // h0 = 0, read by c=0 of segment 0

  float W[64];
  for (int s = 0; s < SS; ++s) {
    // load my W_hh row (16 x float4; L2-resident after first blocks touch it)
    const float* wr = W_hh + ((size_t)s * HH + lane) * HH;
#pragma unroll
    for (int j = 0; j < 64; j += 4) {
      float4 v = *(const float4*)(wr + j);
      W[j] = v.x; W[j + 1] = v.y; W[j + 2] = v.z; W[j + 3] = v.w;
    }
    const float bias = b_hh[s * HH + lane];
    const float* xps = xp + ((size_t)b * TT + s * CC) * HH + lane;

    float xv0 = xps[0];
    float xv1 = xps[HH];
    for (int c = 0; c < CC; ++c) {
      // prefetch xp two steps ahead (off the dependent chain)
      float xvn = (c + 2 < CC) ? xps[(c + 2) * HH] : 0.f;
      const int cp = (c == 0) ? CC - 1 : c - 1;
      float a0 = xv0 + bias, a1 = 0.f, a2 = 0.f, a3 = 0.f;
#pragma unroll
      for (int j4 = 0; j4 < 16; ++j4) {
        float4 hv = *(const float4*)&hist[cp][j4 * 4];  // broadcast read
        a0 += W[j4 * 4 + 0] * hv.x;
        a1 += W[j4 * 4 + 1] * hv.y;
        a2 += W[j4 * 4 + 2] * hv.z;
        a3 += W[j4 * 4 + 3] * hv.w;
      }
      float z = (a0 + a1) + (a2 + a3);
      // tanh(z) = 1 - 2/(exp(2z)+1)  (stable both directions)
      float e = __expf(2.f * z);
      float h = 1.f - 2.f / (e + 1.f);
      hist[c][lane] = h;
      xv0 = xv1;
      xv1 = xvn;
    }

    // fused head for this segment: lane l -> y[b, s*CC + l]
    const float fb = fc_b[s];
    const float* fw = fc_w + s * HH;  // wave-uniform -> scalar loads
#pragma unroll
    for (int base = 0; base < CC; base += 64) {
      int l = base + lane;
      if (l < CC) {
        float z = fb;
#pragma unroll
        for (int i = 0; i < 64; i += 4) {
          float4 hv = *(const float4*)&hist[l][i];
          z += hv.x * fw[i] + hv.y * fw[i + 1] + hv.z * fw[i + 2] +
               hv.w * fw[i + 3];
        }
        y[(size_t)b * TT + s * CC + l] = 1.f / (1.f + __expf(-z));
      }
    }
  }
}

extern "C" void kernel_launch(void* const* d_in, const int* in_sizes, int n_in,
                              void* d_out, int out_size, void* d_ws,
                              size_t ws_size, hipStream_t stream) {
  const float* x    = (const float*)d_in[0];
  const float* W_ih = (const float*)d_in[1];
  const float* W_hh = (const float*)d_in[2];
  const float* b_ih = (const float*)d_in[3];
  const float* b_hh = (const float*)d_in[4];
  const float* fc_w = (const float*)d_in[5];
  const float* fc_b = (const float*)d_in[6];
  float* y  = (float*)d_out;
  float* xp = (float*)d_ws;  // [B][T][H] fp32 = 65.5 MB

  proj_kernel<<<dim3(400, 10), 256, 0, stream>>>(x, W_ih, b_ih, xp);
  rnn_kernel<<<256, 64, 0, stream>>>(xp, W_hh, b_hh, fc_w, fc_b, y);
}

// Round 2
// 509.056 us; speedup vs baseline: 1.0812x; 1.0812x over previous
//
#include <hip/hip_runtime.h>
#include <cstdint>

#define BB 256
#define TT 1000
#define DD 256
#define SS 10
#define HH 64
#define CC 100

// ---------------------------------------------------------------------------
// Kernel 1: input projection  xp[b,t,h] = x[b,t,:] . W_ih[s(t),h,:] + bias
// bias = b_ih[s,h] + b_hh[s,h]  (b_hh folded here, off the rnn serial chain)
// ---------------------------------------------------------------------------
__global__ __launch_bounds__(256) void proj_kernel(
    const float* __restrict__ x, const float* __restrict__ W_ih,
    const float* __restrict__ b_ih, const float* __restrict__ b_hh,
    float* __restrict__ xp) {
  __shared__ float As[64][68];
  __shared__ float Bs[64][68];
  const int s = blockIdx.y;
  const int r0 = blockIdx.x * 64;   // row within segment, r = b*CC + c
  const int tid = threadIdx.x;
  const int ty = tid >> 4, tx = tid & 15;
  const int ty4 = ty * 4, tx4 = tx * 4;
  float acc[4][4] = {{0.f, 0.f, 0.f, 0.f}};

  for (int kc = 0; kc < 4; ++kc) {
#pragma unroll
    for (int m = 0; m < 4; ++m) {
      int f = m * 256 + tid;
      int row = f >> 4, kq = f & 15;
      int r = r0 + row;
      int b = r / CC, c = r - b * CC;
      const float4 av = *(const float4*)(
          x + ((size_t)b * TT + s * CC + c) * DD + kc * 64 + kq * 4);
      *(float4*)&As[row][kq * 4] = av;
      const float4 wv = *(const float4*)(
          W_ih + ((size_t)s * HH + row) * DD + kc * 64 + kq * 4);
      *(float4*)&Bs[row][kq * 4] = wv;
    }
    __syncthreads();
#pragma unroll 4
    for (int k = 0; k < 64; k += 4) {
      float4 a[4], w[4];
#pragma unroll
      for (int i = 0; i < 4; ++i) a[i] = *(const float4*)&As[ty4 + i][k];
#pragma unroll
      for (int j = 0; j < 4; ++j) w[j] = *(const float4*)&Bs[tx4 + j][k];
#pragma unroll
      for (int i = 0; i < 4; ++i)
#pragma unroll
        for (int j = 0; j < 4; ++j)
          acc[i][j] += a[i].x * w[j].x + a[i].y * w[j].y +
                       a[i].z * w[j].z + a[i].w * w[j].w;
    }
    __syncthreads();
  }

  const float4 b1 = *(const float4*)(b_ih + s * HH + tx4);
  const float4 b2 = *(const float4*)(b_hh + s * HH + tx4);
#pragma unroll
  for (int i = 0; i < 4; ++i) {
    int r = r0 + ty4 + i;
    int b = r / CC, c = r - b * CC;
    float4 o;
    o.x = acc[i][0] + b1.x + b2.x;
    o.y = acc[i][1] + b1.y + b2.y;
    o.z = acc[i][2] + b1.z + b2.z;
    o.w = acc[i][3] + b1.w + b2.w;
    *(float4*)(xp + ((size_t)b * TT + s * CC + c) * HH + tx4) = o;
  }
}

// ---------------------------------------------------------------------------
// Kernel 2: recurrence + fused head. One block (one wave) per batch element.
// __launch_bounds__(64, 1): allow up to ~512 VGPRs so W[64] + all 16 in-flight
// float4 LDS reads fit in registers -> pay LDS latency ONCE per step, not 4x.
// ---------------------------------------------------------------------------
__global__ __launch_bounds__(64, 1) void rnn_kernel(
    const float* __restrict__ xp, const float* __restrict__ W_hh,
    const float* __restrict__ fc_w, const float* __restrict__ fc_b,
    float* __restrict__ y) {
  __shared__ float hist[CC][68];
  const int b = blockIdx.x;
  const int lane = threadIdx.x;

  hist[CC - 1][lane] = 0.f;  // h0 = 0, read by c=0 of segment 0

  float W[64];
  for (int s = 0; s < SS; ++s) {
    const float* wr = W_hh + ((size_t)s * HH + lane) * HH;
#pragma unroll
    for (int j = 0; j < 64; j += 4) {
      float4 v = *(const float4*)(wr + j);
      W[j] = v.x; W[j + 1] = v.y; W[j + 2] = v.z; W[j + 3] = v.w;
    }
    const float* xps = xp + ((size_t)b * TT + s * CC) * HH + lane;

    // xp prefetch ring, depth 4 (covers ~900-cyc HBM latency vs ~400-cyc step)
    float xq0 = xps[0];
    float xq1 = xps[1 * HH];
    float xq2 = xps[2 * HH];
    float xq3 = xps[3 * HH];
    for (int c = 0; c < CC; ++c) {
      float xnext = (c + 4 < CC) ? xps[(c + 4) * HH] : 0.f;
      const int cp = (c == 0) ? CC - 1 : c - 1;
      // issue ALL 16 broadcast reads back-to-back, then FMA
      float4 hv[16];
#pragma unroll
      for (int j4 = 0; j4 < 16; ++j4)
        hv[j4] = *(const float4*)&hist[cp][j4 * 4];
      float a0 = xq0, a1 = 0.f, a2 = 0.f, a3 = 0.f;
#pragma unroll
      for (int j4 = 0; j4 < 16; ++j4) {
        a0 += W[j4 * 4 + 0] * hv[j4].x;
        a1 += W[j4 * 4 + 1] * hv[j4].y;
        a2 += W[j4 * 4 + 2] * hv[j4].z;
        a3 += W[j4 * 4 + 3] * hv[j4].w;
      }
      float z = (a0 + a1) + (a2 + a3);
      // tanh(z) = 1 - 2/(exp(2z)+1); raw v_rcp keeps the chain short
      float e = __expf(2.f * z);
      float h = 1.f - 2.f * __builtin_amdgcn_rcpf(e + 1.f);
      hist[c][lane] = h;
      xq0 = xq1; xq1 = xq2; xq2 = xq3; xq3 = xnext;
    }

    // fused head for this segment: lane l -> y[b, s*CC + l]
    const float fb = fc_b[s];
    const float* fw = fc_w + s * HH;  // wave-uniform -> scalar loads
#pragma unroll
    for (int base = 0; base < CC; base += 64) {
      int l = base + lane;
      if (l < CC) {
        float z = fb;
#pragma unroll
        for (int i = 0; i < 64; i += 4) {
          float4 hv = *(const float4*)&hist[l][i];
          z += hv.x * fw[i] + hv.y * fw[i + 1] + hv.z * fw[i + 2] +
               hv.w * fw[i + 3];
        }
        y[(size_t)b * TT + s * CC + l] =
            __builtin_amdgcn_rcpf(1.f + __expf(-z));
      }
    }
  }
}

extern "C" void kernel_launch(void* const* d_in, const int* in_sizes, int n_in,
                              void* d_out, int out_size, void* d_ws,
                              size_t ws_size, hipStream_t stream) {
  const float* x    = (const float*)d_in[0];
  const float* W_ih = (const float*)d_in[1];
  const float* W_hh = (const float*)d_in[2];
  const float* b_ih = (const float*)d_in[3];
  const float* b_hh = (const float*)d_in[4];
  const float* fc_w = (const float*)d_in[5];
  const float* fc_b = (const float*)d_in[6];
  float* y  = (float*)d_out;
  float* xp = (float*)d_ws;  // [B][T][H] fp32 = 65.5 MB

  proj_kernel<<<dim3(400, 10), 256, 0, stream>>>(x, W_ih, b_ih, b_hh, xp);
  rnn_kernel<<<256, 64, 0, stream>>>(xp, W_hh, fc_w, fc_b, y);
}

// Round 3
// 477.818 us; speedup vs baseline: 1.1519x; 1.0654x over previous
//
#include <hip/hip_runtime.h>
#include <cstdint>

#define BB 256
#define TT 1000
#define DD 256
#define SS 10
#define HH 64
#define CC 100

// ---------------------------------------------------------------------------
// Kernel 1: input projection  xp[b,t,h] = x[b,t,:] . W_ih[s(t),h,:] + bias
// bias = b_ih[s,h] + b_hh[s,h]  (b_hh folded here, off the rnn serial chain)
// ---------------------------------------------------------------------------
__global__ __launch_bounds__(256) void proj_kernel(
    const float* __restrict__ x, const float* __restrict__ W_ih,
    const float* __restrict__ b_ih, const float* __restrict__ b_hh,
    float* __restrict__ xp) {
  __shared__ float As[64][68];
  __shared__ float Bs[64][68];
  const int s = blockIdx.y;
  const int r0 = blockIdx.x * 64;   // row within segment, r = b*CC + c
  const int tid = threadIdx.x;
  const int ty = tid >> 4, tx = tid & 15;
  const int ty4 = ty * 4, tx4 = tx * 4;
  float acc[4][4] = {{0.f, 0.f, 0.f, 0.f}};

  for (int kc = 0; kc < 4; ++kc) {
#pragma unroll
    for (int m = 0; m < 4; ++m) {
      int f = m * 256 + tid;
      int row = f >> 4, kq = f & 15;
      int r = r0 + row;
      int b = r / CC, c = r - b * CC;
      const float4 av = *(const float4*)(
          x + ((size_t)b * TT + s * CC + c) * DD + kc * 64 + kq * 4);
      *(float4*)&As[row][kq * 4] = av;
      const float4 wv = *(const float4*)(
          W_ih + ((size_t)s * HH + row) * DD + kc * 64 + kq * 4);
      *(float4*)&Bs[row][kq * 4] = wv;
    }
    __syncthreads();
#pragma unroll 4
    for (int k = 0; k < 64; k += 4) {
      float4 a[4], w[4];
#pragma unroll
      for (int i = 0; i < 4; ++i) a[i] = *(const float4*)&As[ty4 + i][k];
#pragma unroll
      for (int j = 0; j < 4; ++j) w[j] = *(const float4*)&Bs[tx4 + j][k];
#pragma unroll
      for (int i = 0; i < 4; ++i)
#pragma unroll
        for (int j = 0; j < 4; ++j)
          acc[i][j] += a[i].x * w[j].x + a[i].y * w[j].y +
                       a[i].z * w[j].z + a[i].w * w[j].w;
    }
    __syncthreads();
  }

  const float4 b1 = *(const float4*)(b_ih + s * HH + tx4);
  const float4 b2 = *(const float4*)(b_hh + s * HH + tx4);
#pragma unroll
  for (int i = 0; i < 4; ++i) {
    int r = r0 + ty4 + i;
    int b = r / CC, c = r - b * CC;
    float4 o;
    o.x = acc[i][0] + b1.x + b2.x;
    o.y = acc[i][1] + b1.y + b2.y;
    o.z = acc[i][2] + b1.z + b2.z;
    o.w = acc[i][3] + b1.w + b2.w;
    *(float4*)(xp + ((size_t)b * TT + s * CC + c) * HH + tx4) = o;
  }
}

// ---------------------------------------------------------------------------
// Kernel 2: recurrence + fused head. One block (one wave) per batch element.
// h broadcast via v_readlane -> SGPR (FMA takes one SGPR operand): the serial
// chain is pure VALU issue (64 readlane + 64 fmac + tanh), NO LDS latency.
// hist ds_write is fire-and-forget, consumed only by the per-segment head.
// ---------------------------------------------------------------------------
__global__ __launch_bounds__(64, 1) void rnn_kernel(
    const float* __restrict__ xp, const float* __restrict__ W_hh,
    const float* __restrict__ fc_w, const float* __restrict__ fc_b,
    float* __restrict__ y) {
  __shared__ float hist[CC][68];
  const int b = blockIdx.x;
  const int lane = threadIdx.x;

  float W[64];
  float h = 0.f;  // lane i owns h[i]; carried in-register across segments
  for (int s = 0; s < SS; ++s) {
    const float* wr = W_hh + ((size_t)s * HH + lane) * HH;
#pragma unroll
    for (int j = 0; j < 64; j += 4) {
      float4 v = *(const float4*)(wr + j);
      W[j] = v.x; W[j + 1] = v.y; W[j + 2] = v.z; W[j + 3] = v.w;
    }
    const float* xps = xp + ((size_t)b * TT + s * CC) * HH + lane;

    // xp prefetch ring, depth 4 (HBM ~900 cyc vs ~300 cyc step)
    float xq0 = xps[0];
    float xq1 = xps[1 * HH];
    float xq2 = xps[2 * HH];
    float xq3 = xps[3 * HH];
    for (int c = 0; c < CC; ++c) {
      float xnext = (c + 4 < CC) ? xps[(c + 4) * HH] : 0.f;
      const unsigned hu = __float_as_uint(h);
      float a0 = xq0, a1 = 0.f, a2 = 0.f, a3 = 0.f;
#pragma unroll
      for (int i = 0; i < 64; i += 4) {
        float h0 = __uint_as_float(__builtin_amdgcn_readlane(hu, i + 0));
        float h1 = __uint_as_float(__builtin_amdgcn_readlane(hu, i + 1));
        float h2 = __uint_as_float(__builtin_amdgcn_readlane(hu, i + 2));
        float h3 = __uint_as_float(__builtin_amdgcn_readlane(hu, i + 3));
        a0 += W[i + 0] * h0;
        a1 += W[i + 1] * h1;
        a2 += W[i + 2] * h2;
        a3 += W[i + 3] * h3;
      }
      float z = (a0 + a1) + (a2 + a3);
      // tanh(z) = 1 - 2/(exp(2z)+1); raw v_rcp keeps the chain short
      float e = __expf(2.f * z);
      h = 1.f - 2.f * __builtin_amdgcn_rcpf(e + 1.f);
      hist[c][lane] = h;  // off-chain: only the head reads this
      xq0 = xq1; xq1 = xq2; xq2 = xq3; xq3 = xnext;
    }

    // fused head for this segment: lane l -> y[b, s*CC + l]
    const float fb = fc_b[s];
    const float* fw = fc_w + s * HH;  // wave-uniform -> scalar loads
#pragma unroll
    for (int base = 0; base < CC; base += 64) {
      int l = base + lane;
      if (l < CC) {
        float z = fb;
#pragma unroll
        for (int i = 0; i < 64; i += 4) {
          float4 hv = *(const float4*)&hist[l][i];
          z += hv.x * fw[i] + hv.y * fw[i + 1] + hv.z * fw[i + 2] +
               hv.w * fw[i + 3];
        }
        y[(size_t)b * TT + s * CC + l] =
            __builtin_amdgcn_rcpf(1.f + __expf(-z));
      }
    }
  }
}

extern "C" void kernel_launch(void* const* d_in, const int* in_sizes, int n_in,
                              void* d_out, int out_size, void* d_ws,
                              size_t ws_size, hipStream_t stream) {
  const float* x    = (const float*)d_in[0];
  const float* W_ih = (const float*)d_in[1];
  const float* W_hh = (const float*)d_in[2];
  const float* b_ih = (const float*)d_in[3];
  const float* b_hh = (const float*)d_in[4];
  const float* fc_w = (const float*)d_in[5];
  const float* fc_b = (const float*)d_in[6];
  float* y  = (float*)d_out;
  float* xp = (float*)d_ws;  // [B][T][H] fp32 = 65.5 MB

  proj_kernel<<<dim3(400, 10), 256, 0, stream>>>(x, W_ih, b_ih, b_hh, xp);
  rnn_kernel<<<256, 64, 0, stream>>>(xp, W_hh, fc_w, fc_b, y);
}

// Round 4
// 448.309 us; speedup vs baseline: 1.2277x; 1.0658x over previous
//
#include <hip/hip_runtime.h>
#include <cstdint>

#define BB 256
#define TT 1000
#define DD 256
#define SS 10
#define HH 64
#define CC 100

// ---------------------------------------------------------------------------
// Kernel 1: input projection  xp[b,t,h] = x[b,t,:] . W_ih[s(t),h,:] + bias
// bias = b_ih[s,h] + b_hh[s,h]  (b_hh folded here, off the rnn serial chain)
// ---------------------------------------------------------------------------
__global__ __launch_bounds__(256) void proj_kernel(
    const float* __restrict__ x, const float* __restrict__ W_ih,
    const float* __restrict__ b_ih, const float* __restrict__ b_hh,
    float* __restrict__ xp) {
  __shared__ float As[64][68];
  __shared__ float Bs[64][68];
  const int s = blockIdx.y;
  const int r0 = blockIdx.x * 64;   // row within segment, r = b*CC + c
  const int tid = threadIdx.x;
  const int ty = tid >> 4, tx = tid & 15;
  const int ty4 = ty * 4, tx4 = tx * 4;
  float acc[4][4] = {{0.f, 0.f, 0.f, 0.f}};

  for (int kc = 0; kc < 4; ++kc) {
#pragma unroll
    for (int m = 0; m < 4; ++m) {
      int f = m * 256 + tid;
      int row = f >> 4, kq = f & 15;
      int r = r0 + row;
      int b = r / CC, c = r - b * CC;
      const float4 av = *(const float4*)(
          x + ((size_t)b * TT + s * CC + c) * DD + kc * 64 + kq * 4);
      *(float4*)&As[row][kq * 4] = av;
      const float4 wv = *(const float4*)(
          W_ih + ((size_t)s * HH + row) * DD + kc * 64 + kq * 4);
      *(float4*)&Bs[row][kq * 4] = wv;
    }
    __syncthreads();
#pragma unroll 4
    for (int k = 0; k < 64; k += 4) {
      float4 a[4], w[4];
#pragma unroll
      for (int i = 0; i < 4; ++i) a[i] = *(const float4*)&As[ty4 + i][k];
#pragma unroll
      for (int j = 0; j < 4; ++j) w[j] = *(const float4*)&Bs[tx4 + j][k];
#pragma unroll
      for (int i = 0; i < 4; ++i)
#pragma unroll
        for (int j = 0; j < 4; ++j)
          acc[i][j] += a[i].x * w[j].x + a[i].y * w[j].y +
                       a[i].z * w[j].z + a[i].w * w[j].w;
    }
    __syncthreads();
  }

  const float4 b1 = *(const float4*)(b_ih + s * HH + tx4);
  const float4 b2 = *(const float4*)(b_hh + s * HH + tx4);
#pragma unroll
  for (int i = 0; i < 4; ++i) {
    int r = r0 + ty4 + i;
    int b = r / CC, c = r - b * CC;
    float4 o;
    o.x = acc[i][0] + b1.x + b2.x;
    o.y = acc[i][1] + b1.y + b2.y;
    o.z = acc[i][2] + b1.z + b2.z;
    o.w = acc[i][3] + b1.w + b2.w;
    *(float4*)(xp + ((size_t)b * TT + s * CC + c) * HH + tx4) = o;
  }
}

// ---------------------------------------------------------------------------
// Kernel 2: recurrence + fused head. One block (one wave) per batch element.
// h broadcast via ds_bpermute (VGPR->VGPR, no SGPR-write hazard).
// xp prefetch: unroll-4 with per-slot direct load-to-use 4 steps later, so
// the vmcnt wait lands 4 iterations downstream (NOT on the serial chain --
// the R1-R3 rotation ring forced a vmcnt wait every step at the rotate movs).
// ---------------------------------------------------------------------------
__global__ __launch_bounds__(64, 1) void rnn_kernel(
    const float* __restrict__ xp, const float* __restrict__ W_hh,
    const float* __restrict__ fc_w, const float* __restrict__ fc_b,
    float* __restrict__ y) {
  __shared__ float hist[CC][68];
  const int b = blockIdx.x;
  const int lane = threadIdx.x;

  float W[64];
  float h = 0.f;  // lane i owns h[i]; carried in-register across segments
  for (int s = 0; s < SS; ++s) {
    const float* wr = W_hh + ((size_t)s * HH + lane) * HH;
#pragma unroll
    for (int j = 0; j < 64; j += 4) {
      float4 v = *(const float4*)(wr + j);
      W[j] = v.x; W[j + 1] = v.y; W[j + 2] = v.z; W[j + 3] = v.w;
    }
    const float* xps = xp + ((size_t)b * TT + s * CC) * HH + lane;

    float xq0 = xps[0 * HH];
    float xq1 = xps[1 * HH];
    float xq2 = xps[2 * HH];
    float xq3 = xps[3 * HH];

    for (int c4 = 0; c4 < 25; ++c4) {
#pragma unroll
      for (int u = 0; u < 4; ++u) {
        const int c = c4 * 4 + u;
        const float xv = (u == 0) ? xq0 : (u == 1) ? xq1 : (u == 2) ? xq2 : xq3;
        const int hu = __float_as_int(h);
        float a0 = xv, a1 = 0.f, a2 = 0.f, a3 = 0.f;
#pragma unroll
        for (int j = 0; j < 64; j += 4) {
          float h0 = __int_as_float(__builtin_amdgcn_ds_bpermute((j + 0) * 4, hu));
          float h1 = __int_as_float(__builtin_amdgcn_ds_bpermute((j + 1) * 4, hu));
          float h2 = __int_as_float(__builtin_amdgcn_ds_bpermute((j + 2) * 4, hu));
          float h3 = __int_as_float(__builtin_amdgcn_ds_bpermute((j + 3) * 4, hu));
          a0 += W[j + 0] * h0;
          a1 += W[j + 1] * h1;
          a2 += W[j + 2] * h2;
          a3 += W[j + 3] * h3;
        }
        float z = (a0 + a1) + (a2 + a3);
        // tanh(z) = 1 - 2/(exp(2z)+1)
        float e = __expf(2.f * z);
        h = 1.f - 2.f * __builtin_amdgcn_rcpf(e + 1.f);
        hist[c][lane] = h;  // off-chain: only the head reads this
        // reload this slot for step c+4: direct def, consumed next c4 round
        if (c4 < 24) {
          const float xn = xps[(c + 4) * HH];
          if (u == 0) xq0 = xn;
          else if (u == 1) xq1 = xn;
          else if (u == 2) xq2 = xn;
          else xq3 = xn;
        }
      }
    }

    // fused head for this segment: lane l -> y[b, s*CC + l]
    const float fb = fc_b[s];
    const float* fw = fc_w + s * HH;  // wave-uniform -> scalar loads
#pragma unroll
    for (int base = 0; base < CC; base += 64) {
      int l = base + lane;
      if (l < CC) {
        float z = fb;
#pragma unroll
        for (int i = 0; i < 64; i += 4) {
          float4 hv = *(const float4*)&hist[l][i];
          z += hv.x * fw[i] + hv.y * fw[i + 1] + hv.z * fw[i + 2] +
               hv.w * fw[i + 3];
        }
        y[(size_t)b * TT + s * CC + l] =
            __builtin_amdgcn_rcpf(1.f + __expf(-z));
      }
    }
  }
}

extern "C" void kernel_launch(void* const* d_in, const int* in_sizes, int n_in,
                              void* d_out, int out_size, void* d_ws,
                              size_t ws_size, hipStream_t stream) {
  const float* x    = (const float*)d_in[0];
  const float* W_ih = (const float*)d_in[1];
  const float* W_hh = (const float*)d_in[2];
  const float* b_ih = (const float*)d_in[3];
  const float* b_hh = (const float*)d_in[4];
  const float* fc_w = (const float*)d_in[5];
  const float* fc_b = (const float*)d_in[6];
  float* y  = (float*)d_out;
  float* xp = (float*)d_ws;  // [B][T][H] fp32 = 65.5 MB

  proj_kernel<<<dim3(400, 10), 256, 0, stream>>>(x, W_ih, b_ih, b_hh, xp);
  rnn_kernel<<<256, 64, 0, stream>>>(xp, W_hh, fc_w, fc_b, y);
}